// Round 7
// baseline (447.466 us; speedup 1.0000x reference)
//
#include <hip/hip_runtime.h>
#include <math.h>

#define NB    8
#define NPTS  4096
#define NTH   1024
#define SPT   4
#define NFILT 16
#define MAXQ  64          // queue chunk == bits in the hit mask
#define MAXU  256
#define MAXK  256

// d_ws layout (needs ~1.1 MB; ws is much larger)
#define WS_PCNT 0         // u32[8]  active-pred count per batch
#define WS_TCNT 32        // u32[8]  active-targ count per batch
#define WS_PKEY 4096      // u64[8][4096] pred keys (conf desc, idx asc)
#define WS_PPOS 266240    // float4[8][4096] pred pos (normalized) + idx in .w
#define WS_TPOS 790528    // float4[8][4096] targ pos (real coords) + idx in .w

__device__ __forceinline__ int blockReduceSumI(int v, int* scr, int tid) {
    #pragma unroll
    for (int o = 32; o > 0; o >>= 1) v += __shfl_down(v, o, 64);
    if ((tid & 63) == 0) scr[tid >> 6] = v;
    __syncthreads();
    if (tid == 0) {
        int s = 0;
        #pragma unroll
        for (int w = 0; w < NTH / 64; ++w) s += scr[w];
        scr[16] = s;
    }
    __syncthreads();
    return scr[16];
}

__device__ __forceinline__ float blockReduceSumF(float v, float* scr, int tid) {
    #pragma unroll
    for (int o = 32; o > 0; o >>= 1) v += __shfl_down(v, o, 64);
    if ((tid & 63) == 0) scr[tid >> 6] = v;
    __syncthreads();
    if (tid == 0) {
        float s = 0.0f;
        #pragma unroll
        for (int w = 0; w < NTH / 64; ++w) s += scr[w];
        scr[16] = s;
    }
    __syncthreads();
    return scr[16];
}

__device__ __forceinline__ float rowAngleDeg(float a0, float a1, float a2,
                                             float b0, float b1, float b2) {
    float dot = a0 * b0 + a1 * b1 + a2 * b2;
    float na = sqrtf(a0 * a0 + a1 * a1 + a2 * a2);
    float nb = sqrtf(b0 * b0 + b1 * b1 + b2 * b2);
    float c = dot / (na * nb);
    c = fminf(1.0f, fmaxf(-1.0f, c));
    return acosf(c) * 57.29577951308232f;  // /pi*180
}

// Prep: full-chip parallel load + compact actives into ws. 256 blocks x 256.
__global__ __launch_bounds__(256) void prep_kernel(const float* __restrict__ pred,
                                                   const float* __restrict__ targ,
                                                   unsigned char* __restrict__ ws) {
    unsigned int* pcnt = (unsigned int*)(ws + WS_PCNT);
    unsigned int* tcnt = (unsigned int*)(ws + WS_TCNT);
    unsigned long long* pkey = (unsigned long long*)(ws + WS_PKEY);
    float4* ppos = (float4*)(ws + WS_PPOS);
    float4* tpos = (float4*)(ws + WS_TPOS);

    int g = blockIdx.x * 256 + threadIdx.x;   // [0, 65536)
    int tensor = g >> 15;                     // 0 = pred, 1 = targ
    int rbits = g & 32767;
    int batch = rbits >> 12;
    int n = rbits & 4095;
    const float* base = (tensor ? targ : pred)
                        + (size_t)batch * NPTS * 10 + (size_t)n * 10;
    float2 f0 = *(const float2*)base;         // conf_raw, off_z
    float2 f1 = *(const float2*)(base + 2);   // off_x, off_y
    float gz = (float)(n >> 10);
    float gx = (float)((n >> 5) & 31);
    float gy = (float)(n & 31);
    if (tensor == 0) {
        float conf = 1.0f / (1.0f + expf(-f0.x));   // jax.nn.sigmoid
        if (conf > 0.5f) {
            unsigned int u = ~(__float_as_uint(conf) | 0x80000000u);  // conf desc
            unsigned long long key = ((unsigned long long)u << 32) | (unsigned int)n;
            unsigned int e = atomicAdd(&pcnt[batch], 1u);  // wave-coalesced
            pkey[batch * NPTS + e] = key;
            ppos[batch * NPTS + e] = make_float4((f0.y + gz) * 0.25f,
                                                 (f1.x + gx) * 0.03125f,
                                                 (f1.y + gy) * 0.03125f,
                                                 (float)n);
        }
    } else {
        if (f0.x > 0.5f) {
            unsigned int e = atomicAdd(&tcnt[batch], 1u);
            tpos[batch * NPTS + e] = make_float4((f0.y + gz) * 0.25f * 25.0f,
                                                 (f1.x + gx) * 0.03125f * 25.0f,
                                                 (f1.y + gy) * 0.03125f * 4.0f,
                                                 (float)n);
        }
    }
}

// Main: one block per batch, operates on compacted records only.
__global__ __launch_bounds__(NTH) void molan_kernel(const float* __restrict__ pred,
                                                    const float* __restrict__ targ,
                                                    const unsigned char* __restrict__ ws,
                                                    float* __restrict__ out) {
    __shared__ int   scr_i[32];
    __shared__ float scr_f[32];
    __shared__ unsigned long long scr_m[16];
    __shared__ int   cnt[8];
    __shared__ unsigned long long f_key[NFILT];
    __shared__ float f_x[NFILT], f_y[NFILT], f_z[NFILT];
    __shared__ unsigned long long q_key[MAXQ];
    __shared__ float q_x[MAXQ], q_y[MAXQ], q_z[MAXQ];
    __shared__ unsigned long long u_key[MAXU];
    __shared__ float u_x[MAXU], u_y[MAXU], u_z[MAXU];
    __shared__ float k_x[MAXK], k_y[MAXK], k_z[MAXK];
    __shared__ int   k_idx[MAXK];
    __shared__ unsigned int k_match[MAXK];

    const int b = blockIdx.x;
    const int tid = threadIdx.x;
    const float* pb = pred + (size_t)b * NPTS * 10;
    const float* tb = targ + (size_t)b * NPTS * 10;
    const unsigned int* pcnt = (const unsigned int*)(ws + WS_PCNT);
    const unsigned int* tcnt = (const unsigned int*)(ws + WS_TCNT);
    const unsigned long long* pkey = (const unsigned long long*)(ws + WS_PKEY) + b * NPTS;
    const float4* ppos = (const float4*)(ws + WS_PPOS) + b * NPTS;
    const float4* tpos = (const float4*)(ws + WS_TPOS) + b * NPTS;
    const int np = (int)pcnt[b];
    const int nt = (int)tcnt[b];

    // ---- load compacted records into registers ----
    unsigned long long key[SPT];
    bool  act[SPT];
    int   pidx[SPT];
    float cx[SPT], cy[SPT], cz[SPT];
    #pragma unroll
    for (int s = 0; s < SPT; ++s) {
        int slot = tid + NTH * s;
        bool a = slot < np;
        act[s] = a;
        key[s] = a ? pkey[slot] : ~0ull;
        float4 p = a ? ppos[slot] : make_float4(0.f, 0.f, 0.f, 0.f);
        cx[s] = p.x; cy[s] = p.y; cz[s] = p.z; pidx[s] = (int)p.w;
    }
    bool  t_act[SPT];
    int   t_n[SPT];
    float t_x[SPT], t_y[SPT], t_z[SPT];
    #pragma unroll
    for (int s = 0; s < SPT; ++s) {
        int slot = tid + NTH * s;
        bool a = slot < nt;
        t_act[s] = a;
        float4 p = a ? tpos[slot] : make_float4(0.f, 0.f, 0.f, 0.f);
        t_x[s] = p.x; t_y[s] = p.y; t_z[s] = p.z; t_n[s] = (int)p.w;
    }

    // ---- NMS fixpoint (exact reference semantics, order via keys) ----
    int cur = np;
    int prev = -1;
    while (cur != prev) {
        // filter = per-wave confidence champion (min key among actives)
        {
            unsigned long long bk = ~0ull;
            float bx = 0.f, by = 0.f, bz = 0.f;
            #pragma unroll
            for (int s = 0; s < SPT; ++s)
                if (act[s] && key[s] < bk) { bk = key[s]; bx = cx[s]; by = cy[s]; bz = cz[s]; }
            #pragma unroll
            for (int o = 32; o > 0; o >>= 1) {
                unsigned long long ok = __shfl_xor(bk, o, 64);
                float ox = __shfl_xor(bx, o, 64);
                float oy = __shfl_xor(by, o, 64);
                float oz = __shfl_xor(bz, o, 64);
                if (ok < bk) { bk = ok; bx = ox; by = oy; bz = oz; }
            }
            if ((tid & 63) == 0) {
                int w = tid >> 6;
                f_key[w] = bk; f_x[w] = bx; f_y[w] = by; f_z[w] = bz;
            }
        }
        __syncthreads();

        // pass 1: s[j] = exists active i (key_i<key_j) within cutoff
        bool sflag[SPT], pend[SPT];
        #pragma unroll
        for (int s = 0; s < SPT; ++s) {
            sflag[s] = false; pend[s] = false;
            if (!act[s]) continue;
            bool found = false;
            for (int f = 0; f < NFILT; ++f) {
                if (f_key[f] < key[s]) {
                    float dx = f_x[f] - cx[s], dy = f_y[f] - cy[s], dz = f_z[f] - cz[s];
                    if (dx * dx + dy * dy + dz * dz < 4.0f) { found = true; break; }
                }
            }
            if (found) sflag[s] = true;
            else pend[s] = true;
        }
        // chunked cooperative resolve: enqueue-then-check, hit-mask reduction
        while (true) {
            if (tid == 0) cnt[1] = 0;
            __syncthreads();   // also fences prior q_*/scr_m reads vs rewrites
            int qe[SPT];
            #pragma unroll
            for (int s = 0; s < SPT; ++s) {
                qe[s] = -1;
                if (pend[s]) {
                    int e = atomicAdd(&cnt[1], 1);
                    if (e < MAXQ) {
                        q_key[e] = key[s]; q_x[e] = cx[s]; q_y[e] = cy[s]; q_z[e] = cz[s];
                        qe[s] = e; pend[s] = false;
                    }
                }
            }
            __syncthreads();
            if (cnt[1] == 0) break;
            const int Q = min(cnt[1], MAXQ);
            unsigned long long mask = 0;
            for (int e = 0; e < Q; ++e) {     // uniform loop, all lanes present
                unsigned long long qk = q_key[e];
                float qx = q_x[e], qy = q_y[e], qz = q_z[e];
                bool hit = false;
                #pragma unroll
                for (int s = 0; s < SPT; ++s) {
                    if (act[s] && key[s] < qk) {
                        float dx = cx[s] - qx, dy = cy[s] - qy, dz = cz[s] - qz;
                        if (dx * dx + dy * dy + dz * dz < 4.0f) hit = true;
                    }
                }
                if (hit) mask |= (1ull << e);
            }
            #pragma unroll
            for (int o = 32; o > 0; o >>= 1) mask |= __shfl_xor(mask, o, 64);
            if ((tid & 63) == 0) scr_m[tid >> 6] = mask;
            __syncthreads();
            unsigned long long full = 0;
            #pragma unroll
            for (int w = 0; w < NTH / 64; ++w) full |= scr_m[w];
            #pragma unroll
            for (int s = 0; s < SPT; ++s)
                if (qe[s] >= 0) sflag[s] = (full >> qe[s]) & 1ull;
        }

        // pass 2: supp[j] = exists u in U={active,!s} with key_u<key_j, d<cutoff
        bool upend[SPT], supp[SPT];
        #pragma unroll
        for (int s = 0; s < SPT; ++s) {
            upend[s] = act[s] && !sflag[s];
            supp[s] = false;
        }
        while (true) {
            if (tid == 0) cnt[2] = 0;
            __syncthreads();   // fences prior u_* reads vs rewrites
            #pragma unroll
            for (int s = 0; s < SPT; ++s) {
                if (upend[s]) {
                    int e = atomicAdd(&cnt[2], 1);
                    if (e < MAXU) {
                        u_key[e] = key[s]; u_x[e] = cx[s]; u_y[e] = cy[s]; u_z[e] = cz[s];
                        upend[s] = false;
                    }
                }
            }
            __syncthreads();
            if (cnt[2] == 0) break;
            const int Ku = min(cnt[2], MAXU);
            #pragma unroll
            for (int s = 0; s < SPT; ++s) {
                if (!act[s] || supp[s]) continue;
                for (int e = 0; e < Ku; ++e) {
                    if (u_key[e] < key[s]) {
                        float dx = u_x[e] - cx[s], dy = u_y[e] - cy[s], dz = u_z[e] - cz[s];
                        if (dx * dx + dy * dy + dz * dz < 4.0f) { supp[s] = true; break; }
                    }
                }
            }
        }
        // commit
        int loc = 0;
        #pragma unroll
        for (int s = 0; s < SPT; ++s) {
            if (act[s] && supp[s]) act[s] = false;
            loc += act[s] ? 1 : 0;
        }
        prev = cur;
        cur = blockReduceSumI(loc, scr_i, tid);
    }
    const int n_pd = cur;

    // ---- matching: kept preds (chunked) vs all targets, lowest target idx ----
    bool kpend[SPT];
    #pragma unroll
    for (int s = 0; s < SPT; ++s) kpend[s] = act[s];
    int loc_tp = 0;
    float loc_ang = 0.0f;
    while (true) {
        if (tid == 0) cnt[3] = 0;
        __syncthreads();   // fences prior k_* reads vs rewrites
        #pragma unroll
        for (int s = 0; s < SPT; ++s) {
            if (kpend[s]) {
                int e = atomicAdd(&cnt[3], 1);
                if (e < MAXK) {
                    k_x[e] = cx[s] * 25.0f; k_y[e] = cy[s] * 25.0f; k_z[e] = cz[s] * 4.0f;
                    k_idx[e] = pidx[s];
                    k_match[e] = 0xFFFFFFFFu;
                    kpend[s] = false;
                }
            }
        }
        __syncthreads();
        if (cnt[3] == 0) break;
        const int K = min(cnt[3], MAXK);
        #pragma unroll
        for (int s = 0; s < SPT; ++s) {
            if (!t_act[s]) continue;
            float tx = t_x[s], ty = t_y[s], tz = t_z[s];
            for (int e = 0; e < K; ++e) {
                float dx = tx - k_x[e], dy = ty - k_y[e], dz = tz - k_z[e];
                if (dx * dx + dy * dy + dz * dz < 4.0f)
                    atomicMin(&k_match[e], (unsigned int)t_n[s]);  // few hits
            }
        }
        __syncthreads();
        if (tid < K) {
            unsigned int m = k_match[tid];
            if (m != 0xFFFFFFFFu) {
                ++loc_tp;
                const float2* pr = (const float2*)(pb + (size_t)k_idx[tid] * 10 + 4);
                float2 p0 = pr[0], p1 = pr[1], p2v = pr[2];
                float ax0 = p0.x, ax1 = p0.y, ax2 = p1.x;
                float ay0 = p1.y, ay1 = p2v.x, ay2 = p2v.y;
                float az0 = ax1 * ay2 - ax2 * ay1;
                float az1 = ax2 * ay0 - ax0 * ay2;
                float az2 = ax0 * ay1 - ax1 * ay0;
                const float2* tr = (const float2*)(tb + (size_t)m * 10 + 4);
                float2 t0 = tr[0], t1 = tr[1], t2v = tr[2];
                float bx0 = t0.x, bx1 = t0.y, bx2 = t1.x;
                float by0 = t1.y, by1 = t2v.x, by2 = t2v.y;
                float bz0 = bx1 * by2 - bx2 * by1;
                float bz1 = bx2 * by0 - bx0 * by2;
                float bz2 = bx0 * by1 - bx1 * by0;
                loc_ang += rowAngleDeg(ax0, ax1, ax2, bx0, bx1, bx2);
                loc_ang += rowAngleDeg(ay0, ay1, ay2, by0, by1, by2);
                loc_ang += rowAngleDeg(az0, az1, az2, bz0, bz1, bz2);
            }
        }
    }

    int tp = blockReduceSumI(loc_tp, scr_i, tid);
    float angsum = blockReduceSumF(loc_ang, scr_f, tid);

    if (tid == 0) {
        out[b * 3 + 0] = (float)tp;
        out[b * 3 + 1] = (float)(n_pd - tp);
        out[b * 3 + 2] = (float)(nt - tp);
        out[NB * 3 + b] = (tp > 0) ? (angsum / (3.0f * (float)tp)) : 0.0f;
    }
}

extern "C" void kernel_launch(void* const* d_in, const int* in_sizes, int n_in,
                              void* d_out, int out_size, void* d_ws, size_t ws_size,
                              hipStream_t stream) {
    const float* pred = (const float*)d_in[0];
    const float* targ = (const float*)d_in[1];
    float* out = (float*)d_out;
    unsigned char* ws = (unsigned char*)d_ws;
    hipMemsetAsync(ws, 0, 64, stream);                 // zero compaction counters
    prep_kernel<<<dim3(256), dim3(256), 0, stream>>>(pred, targ, ws);
    molan_kernel<<<dim3(NB), dim3(NTH), 0, stream>>>(pred, targ, ws, out);
}

// Round 8
// 79.344 us; speedup vs baseline: 5.6396x; 5.6396x over previous
//
#include <hip/hip_runtime.h>
#include <math.h>

#define NB    8
#define NPTS  4096
#define NTH   1024
#define SPT   4
#define NFILT 16
#define MAXQ  64          // queue chunk == bits in the hit mask
#define MAXU  256
#define MAXK  256

// d_ws layout (needs ~1.1 MB; ws is much larger)
#define WS_PCNT 0         // u32[8]  active-pred count per batch
#define WS_TCNT 32        // u32[8]  active-targ count per batch
#define WS_PKEY 4096      // u64[8][4096] pred keys (conf desc, idx asc)
#define WS_PPOS 266240    // float4[8][4096] pred pos (normalized) + idx in .w
#define WS_TPOS 790528    // float4[8][4096] targ pos (real coords) + idx in .w

__device__ __forceinline__ int blockReduceSumI(int v, int* scr, int tid) {
    #pragma unroll
    for (int o = 32; o > 0; o >>= 1) v += __shfl_down(v, o, 64);
    if ((tid & 63) == 0) scr[tid >> 6] = v;
    __syncthreads();
    if (tid == 0) {
        int s = 0;
        #pragma unroll
        for (int w = 0; w < NTH / 64; ++w) s += scr[w];
        scr[16] = s;
    }
    __syncthreads();
    return scr[16];
}

__device__ __forceinline__ float blockReduceSumF(float v, float* scr, int tid) {
    #pragma unroll
    for (int o = 32; o > 0; o >>= 1) v += __shfl_down(v, o, 64);
    if ((tid & 63) == 0) scr[tid >> 6] = v;
    __syncthreads();
    if (tid == 0) {
        float s = 0.0f;
        #pragma unroll
        for (int w = 0; w < NTH / 64; ++w) s += scr[w];
        scr[16] = s;
    }
    __syncthreads();
    return scr[16];
}

__device__ __forceinline__ float rowAngleDeg(float a0, float a1, float a2,
                                             float b0, float b1, float b2) {
    float dot = a0 * b0 + a1 * b1 + a2 * b2;
    float na = sqrtf(a0 * a0 + a1 * a1 + a2 * a2);
    float nb = sqrtf(b0 * b0 + b1 * b1 + b2 * b2);
    float c = dot / (na * nb);
    c = fminf(1.0f, fmaxf(-1.0f, c));
    return acosf(c) * 57.29577951308232f;  // /pi*180
}

// Prep: full-chip parallel load + hierarchical compaction into ws.
// 256 blocks x 256 threads; each block covers one (tensor,batch) 256-chunk.
// ballot-prefix (0 atomics) -> 1 LDS atomic/wave -> 1 global atomic/block.
__global__ __launch_bounds__(256) void prep_kernel(const float* __restrict__ pred,
                                                   const float* __restrict__ targ,
                                                   unsigned char* __restrict__ ws) {
    __shared__ int lcnt;
    __shared__ int gbase;
    __shared__ int wbase[4];
    unsigned int* pcnt = (unsigned int*)(ws + WS_PCNT);
    unsigned int* tcnt = (unsigned int*)(ws + WS_TCNT);
    unsigned long long* pkey = (unsigned long long*)(ws + WS_PKEY);
    float4* ppos = (float4*)(ws + WS_PPOS);
    float4* tpos = (float4*)(ws + WS_TPOS);

    const int tid = threadIdx.x;
    const int g = blockIdx.x * 256 + tid;     // [0, 65536)
    const int tensor = g >> 15;               // 0 = pred, 1 = targ (block-uniform)
    const int batch = (g >> 12) & 7;          // block-uniform
    const int n = g & 4095;
    const float* base = (tensor ? targ : pred)
                        + (size_t)batch * NPTS * 10 + (size_t)n * 10;
    float2 f0 = *(const float2*)base;         // conf_raw, off_z
    float2 f1 = *(const float2*)(base + 2);   // off_x, off_y
    float gz = (float)(n >> 10);
    float gx = (float)((n >> 5) & 31);
    float gy = (float)(n & 31);

    bool active;
    unsigned long long key = 0;
    float4 rec;
    if (tensor == 0) {
        float conf = 1.0f / (1.0f + expf(-f0.x));   // jax.nn.sigmoid
        active = conf > 0.5f;
        unsigned int u = ~(__float_as_uint(conf) | 0x80000000u);  // conf desc
        key = ((unsigned long long)u << 32) | (unsigned int)n;    // idx asc tiebreak
        rec = make_float4((f0.y + gz) * 0.25f,
                          (f1.x + gx) * 0.03125f,
                          (f1.y + gy) * 0.03125f,
                          (float)n);
    } else {
        active = f0.x > 0.5f;
        rec = make_float4((f0.y + gz) * 0.25f * 25.0f,
                          (f1.x + gx) * 0.03125f * 25.0f,
                          (f1.y + gy) * 0.03125f * 4.0f,
                          (float)n);
    }

    if (tid == 0) lcnt = 0;
    __syncthreads();
    const int lane = tid & 63, wid = tid >> 6;
    unsigned long long ball = __ballot(active);
    int lofs = __popcll(ball & ((1ull << lane) - 1ull));
    if (lane == 0) wbase[wid] = atomicAdd(&lcnt, __popcll(ball));
    __syncthreads();
    if (tid == 0) {
        unsigned int* cp = tensor ? &tcnt[batch] : &pcnt[batch];
        gbase = (int)atomicAdd(cp, (unsigned int)lcnt);   // 1 global atomic/block
    }
    __syncthreads();
    if (active) {
        int e = batch * NPTS + gbase + wbase[wid] + lofs;
        if (tensor == 0) { pkey[e] = key; ppos[e] = rec; }
        else tpos[e] = rec;
    }
}

// Main: one block per batch, operates on compacted records only.
__global__ __launch_bounds__(NTH) void molan_kernel(const float* __restrict__ pred,
                                                    const float* __restrict__ targ,
                                                    const unsigned char* __restrict__ ws,
                                                    float* __restrict__ out) {
    __shared__ int   scr_i[32];
    __shared__ float scr_f[32];
    __shared__ unsigned long long scr_m[16];
    __shared__ int   cnt[8];
    __shared__ unsigned long long f_key[NFILT];
    __shared__ float f_x[NFILT], f_y[NFILT], f_z[NFILT];
    __shared__ unsigned long long q_key[MAXQ];
    __shared__ float q_x[MAXQ], q_y[MAXQ], q_z[MAXQ];
    __shared__ unsigned long long u_key[MAXU];
    __shared__ float u_x[MAXU], u_y[MAXU], u_z[MAXU];
    __shared__ float k_x[MAXK], k_y[MAXK], k_z[MAXK];
    __shared__ int   k_idx[MAXK];
    __shared__ unsigned int k_match[MAXK];

    const int b = blockIdx.x;
    const int tid = threadIdx.x;
    const float* pb = pred + (size_t)b * NPTS * 10;
    const float* tb = targ + (size_t)b * NPTS * 10;
    const unsigned int* pcnt = (const unsigned int*)(ws + WS_PCNT);
    const unsigned int* tcnt = (const unsigned int*)(ws + WS_TCNT);
    const unsigned long long* pkey = (const unsigned long long*)(ws + WS_PKEY) + b * NPTS;
    const float4* ppos = (const float4*)(ws + WS_PPOS) + b * NPTS;
    const float4* tpos = (const float4*)(ws + WS_TPOS) + b * NPTS;
    const int np = (int)pcnt[b];
    const int nt = (int)tcnt[b];

    // ---- load compacted records into registers ----
    unsigned long long key[SPT];
    bool  act[SPT];
    int   pidx[SPT];
    float cx[SPT], cy[SPT], cz[SPT];
    #pragma unroll
    for (int s = 0; s < SPT; ++s) {
        int slot = tid + NTH * s;
        bool a = slot < np;
        act[s] = a;
        key[s] = a ? pkey[slot] : ~0ull;
        float4 p = a ? ppos[slot] : make_float4(0.f, 0.f, 0.f, 0.f);
        cx[s] = p.x; cy[s] = p.y; cz[s] = p.z; pidx[s] = (int)p.w;
    }
    bool  t_act[SPT];
    int   t_n[SPT];
    float t_x[SPT], t_y[SPT], t_z[SPT];
    #pragma unroll
    for (int s = 0; s < SPT; ++s) {
        int slot = tid + NTH * s;
        bool a = slot < nt;
        t_act[s] = a;
        float4 p = a ? tpos[slot] : make_float4(0.f, 0.f, 0.f, 0.f);
        t_x[s] = p.x; t_y[s] = p.y; t_z[s] = p.z; t_n[s] = (int)p.w;
    }

    // ---- NMS fixpoint (exact reference semantics, order via keys) ----
    int cur = np;
    int prev = -1;
    while (cur != prev) {
        // filter = per-wave confidence champion (min key among actives)
        {
            unsigned long long bk = ~0ull;
            float bx = 0.f, by = 0.f, bz = 0.f;
            #pragma unroll
            for (int s = 0; s < SPT; ++s)
                if (act[s] && key[s] < bk) { bk = key[s]; bx = cx[s]; by = cy[s]; bz = cz[s]; }
            #pragma unroll
            for (int o = 32; o > 0; o >>= 1) {
                unsigned long long ok = __shfl_xor(bk, o, 64);
                float ox = __shfl_xor(bx, o, 64);
                float oy = __shfl_xor(by, o, 64);
                float oz = __shfl_xor(bz, o, 64);
                if (ok < bk) { bk = ok; bx = ox; by = oy; bz = oz; }
            }
            if ((tid & 63) == 0) {
                int w = tid >> 6;
                f_key[w] = bk; f_x[w] = bx; f_y[w] = by; f_z[w] = bz;
            }
        }
        __syncthreads();

        // pass 1: s[j] = exists active i (key_i<key_j) within cutoff
        bool sflag[SPT], pend[SPT];
        #pragma unroll
        for (int s = 0; s < SPT; ++s) {
            sflag[s] = false; pend[s] = false;
            if (!act[s]) continue;
            bool found = false;
            for (int f = 0; f < NFILT; ++f) {
                if (f_key[f] < key[s]) {
                    float dx = f_x[f] - cx[s], dy = f_y[f] - cy[s], dz = f_z[f] - cz[s];
                    if (dx * dx + dy * dy + dz * dz < 4.0f) { found = true; break; }
                }
            }
            if (found) sflag[s] = true;
            else pend[s] = true;
        }
        // chunked cooperative resolve: enqueue-then-check, hit-mask reduction
        while (true) {
            if (tid == 0) cnt[1] = 0;
            __syncthreads();   // also fences prior q_*/scr_m reads vs rewrites
            int qe[SPT];
            #pragma unroll
            for (int s = 0; s < SPT; ++s) {
                qe[s] = -1;
                if (pend[s]) {
                    int e = atomicAdd(&cnt[1], 1);
                    if (e < MAXQ) {
                        q_key[e] = key[s]; q_x[e] = cx[s]; q_y[e] = cy[s]; q_z[e] = cz[s];
                        qe[s] = e; pend[s] = false;
                    }
                }
            }
            __syncthreads();
            if (cnt[1] == 0) break;
            const int Q = min(cnt[1], MAXQ);
            unsigned long long mask = 0;
            for (int e = 0; e < Q; ++e) {     // uniform loop, all lanes present
                unsigned long long qk = q_key[e];
                float qx = q_x[e], qy = q_y[e], qz = q_z[e];
                bool hit = false;
                #pragma unroll
                for (int s = 0; s < SPT; ++s) {
                    if (act[s] && key[s] < qk) {
                        float dx = cx[s] - qx, dy = cy[s] - qy, dz = cz[s] - qz;
                        if (dx * dx + dy * dy + dz * dz < 4.0f) hit = true;
                    }
                }
                if (hit) mask |= (1ull << e);
            }
            #pragma unroll
            for (int o = 32; o > 0; o >>= 1) mask |= __shfl_xor(mask, o, 64);
            if ((tid & 63) == 0) scr_m[tid >> 6] = mask;
            __syncthreads();
            unsigned long long full = 0;
            #pragma unroll
            for (int w = 0; w < NTH / 64; ++w) full |= scr_m[w];
            #pragma unroll
            for (int s = 0; s < SPT; ++s)
                if (qe[s] >= 0) sflag[s] = (full >> qe[s]) & 1ull;
        }

        // pass 2: supp[j] = exists u in U={active,!s} with key_u<key_j, d<cutoff
        bool upend[SPT], supp[SPT];
        #pragma unroll
        for (int s = 0; s < SPT; ++s) {
            upend[s] = act[s] && !sflag[s];
            supp[s] = false;
        }
        while (true) {
            if (tid == 0) cnt[2] = 0;
            __syncthreads();   // fences prior u_* reads vs rewrites
            #pragma unroll
            for (int s = 0; s < SPT; ++s) {
                if (upend[s]) {
                    int e = atomicAdd(&cnt[2], 1);
                    if (e < MAXU) {
                        u_key[e] = key[s]; u_x[e] = cx[s]; u_y[e] = cy[s]; u_z[e] = cz[s];
                        upend[s] = false;
                    }
                }
            }
            __syncthreads();
            if (cnt[2] == 0) break;
            const int Ku = min(cnt[2], MAXU);
            #pragma unroll
            for (int s = 0; s < SPT; ++s) {
                if (!act[s] || supp[s]) continue;
                for (int e = 0; e < Ku; ++e) {
                    if (u_key[e] < key[s]) {
                        float dx = u_x[e] - cx[s], dy = u_y[e] - cy[s], dz = u_z[e] - cz[s];
                        if (dx * dx + dy * dy + dz * dz < 4.0f) { supp[s] = true; break; }
                    }
                }
            }
        }
        // commit
        int loc = 0;
        #pragma unroll
        for (int s = 0; s < SPT; ++s) {
            if (act[s] && supp[s]) act[s] = false;
            loc += act[s] ? 1 : 0;
        }
        prev = cur;
        cur = blockReduceSumI(loc, scr_i, tid);
    }
    const int n_pd = cur;

    // ---- matching: kept preds (chunked) vs all targets, lowest target idx ----
    bool kpend[SPT];
    #pragma unroll
    for (int s = 0; s < SPT; ++s) kpend[s] = act[s];
    int loc_tp = 0;
    float loc_ang = 0.0f;
    while (true) {
        if (tid == 0) cnt[3] = 0;
        __syncthreads();   // fences prior k_* reads vs rewrites
        #pragma unroll
        for (int s = 0; s < SPT; ++s) {
            if (kpend[s]) {
                int e = atomicAdd(&cnt[3], 1);
                if (e < MAXK) {
                    k_x[e] = cx[s] * 25.0f; k_y[e] = cy[s] * 25.0f; k_z[e] = cz[s] * 4.0f;
                    k_idx[e] = pidx[s];
                    k_match[e] = 0xFFFFFFFFu;
                    kpend[s] = false;
                }
            }
        }
        __syncthreads();
        if (cnt[3] == 0) break;
        const int K = min(cnt[3], MAXK);
        #pragma unroll
        for (int s = 0; s < SPT; ++s) {
            if (!t_act[s]) continue;
            float tx = t_x[s], ty = t_y[s], tz = t_z[s];
            for (int e = 0; e < K; ++e) {
                float dx = tx - k_x[e], dy = ty - k_y[e], dz = tz - k_z[e];
                if (dx * dx + dy * dy + dz * dz < 4.0f)
                    atomicMin(&k_match[e], (unsigned int)t_n[s]);  // few hits
            }
        }
        __syncthreads();
        if (tid < K) {
            unsigned int m = k_match[tid];
            if (m != 0xFFFFFFFFu) {
                ++loc_tp;
                const float2* pr = (const float2*)(pb + (size_t)k_idx[tid] * 10 + 4);
                float2 p0 = pr[0], p1 = pr[1], p2v = pr[2];
                float ax0 = p0.x, ax1 = p0.y, ax2 = p1.x;
                float ay0 = p1.y, ay1 = p2v.x, ay2 = p2v.y;
                float az0 = ax1 * ay2 - ax2 * ay1;
                float az1 = ax2 * ay0 - ax0 * ay2;
                float az2 = ax0 * ay1 - ax1 * ay0;
                const float2* tr = (const float2*)(tb + (size_t)m * 10 + 4);
                float2 t0 = tr[0], t1 = tr[1], t2v = tr[2];
                float bx0 = t0.x, bx1 = t0.y, bx2 = t1.x;
                float by0 = t1.y, by1 = t2v.x, by2 = t2v.y;
                float bz0 = bx1 * by2 - bx2 * by1;
                float bz1 = bx2 * by0 - bx0 * by2;
                float bz2 = bx0 * by1 - bx1 * by0;
                loc_ang += rowAngleDeg(ax0, ax1, ax2, bx0, bx1, bx2);
                loc_ang += rowAngleDeg(ay0, ay1, ay2, by0, by1, by2);
                loc_ang += rowAngleDeg(az0, az1, az2, bz0, bz1, bz2);
            }
        }
    }

    int tp = blockReduceSumI(loc_tp, scr_i, tid);
    float angsum = blockReduceSumF(loc_ang, scr_f, tid);

    if (tid == 0) {
        out[b * 3 + 0] = (float)tp;
        out[b * 3 + 1] = (float)(n_pd - tp);
        out[b * 3 + 2] = (float)(nt - tp);
        out[NB * 3 + b] = (tp > 0) ? (angsum / (3.0f * (float)tp)) : 0.0f;
    }
}

extern "C" void kernel_launch(void* const* d_in, const int* in_sizes, int n_in,
                              void* d_out, int out_size, void* d_ws, size_t ws_size,
                              hipStream_t stream) {
    const float* pred = (const float*)d_in[0];
    const float* targ = (const float*)d_in[1];
    float* out = (float*)d_out;
    unsigned char* ws = (unsigned char*)d_ws;
    hipMemsetAsync(ws, 0, 64, stream);                 // zero compaction counters
    prep_kernel<<<dim3(256), dim3(256), 0, stream>>>(pred, targ, ws);
    molan_kernel<<<dim3(NB), dim3(NTH), 0, stream>>>(pred, targ, ws, out);
}

// Round 9
// 76.176 us; speedup vs baseline: 5.8741x; 1.0416x over previous
//
#include <hip/hip_runtime.h>
#include <math.h>

#define NB    8
#define NPTS  4096
#define NTH   1024
#define SPT   4
#define NFILT 16
#define MAXQ  512
#define MAXU  256
#define MAXK  256

// d_ws layout (~1.3 MB; no initialization required)
#define WS_PCC  0         // u32[8][16] pred active count per 256-chunk
#define WS_TCC  512       // u32[8][16] targ active count per 256-chunk
#define WS_PKEY 1024      // u64[8][4096] pred keys (chunk-local compaction)
#define WS_PPOS 263168    // float4[8][4096] pred pos (normalized) + idx in .w
#define WS_TPOS 787456    // float4[8][4096] targ pos (real) + idx in .w

__device__ __forceinline__ int blockReduceSumI(int v, int* scr, int tid) {
    #pragma unroll
    for (int o = 32; o > 0; o >>= 1) v += __shfl_down(v, o, 64);
    if ((tid & 63) == 0) scr[tid >> 6] = v;
    __syncthreads();
    if (tid == 0) {
        int s = 0;
        #pragma unroll
        for (int w = 0; w < NTH / 64; ++w) s += scr[w];
        scr[16] = s;
    }
    __syncthreads();
    return scr[16];
}

__device__ __forceinline__ float blockReduceSumF(float v, float* scr, int tid) {
    #pragma unroll
    for (int o = 32; o > 0; o >>= 1) v += __shfl_down(v, o, 64);
    if ((tid & 63) == 0) scr[tid >> 6] = v;
    __syncthreads();
    if (tid == 0) {
        float s = 0.0f;
        #pragma unroll
        for (int w = 0; w < NTH / 64; ++w) s += scr[w];
        scr[16] = s;
    }
    __syncthreads();
    return scr[16];
}

__device__ __forceinline__ float rowAngleDeg(float a0, float a1, float a2,
                                             float b0, float b1, float b2) {
    float dot = a0 * b0 + a1 * b1 + a2 * b2;
    float na = sqrtf(a0 * a0 + a1 * a1 + a2 * a2);
    float nb = sqrtf(b0 * b0 + b1 * b1 + b2 * b2);
    float c = dot / (na * nb);
    c = fminf(1.0f, fmaxf(-1.0f, c));
    return acosf(c) * 57.29577951308232f;  // /pi*180
}

// Prep: full-chip parallel load + chunk-local compaction. 256 blocks x 256.
// Zero global atomics; each block owns one (tensor,batch,chunk) and writes
// its count with a plain store (no counter init needed).
__global__ __launch_bounds__(256) void prep_kernel(const float* __restrict__ pred,
                                                   const float* __restrict__ targ,
                                                   unsigned char* __restrict__ ws) {
    __shared__ int wcnt[4];
    unsigned int* pcc = (unsigned int*)(ws + WS_PCC);
    unsigned int* tcc = (unsigned int*)(ws + WS_TCC);
    unsigned long long* pkey = (unsigned long long*)(ws + WS_PKEY);
    float4* ppos = (float4*)(ws + WS_PPOS);
    float4* tpos = (float4*)(ws + WS_TPOS);

    const int tid = threadIdx.x;
    const int blk = blockIdx.x;
    const int tensor = blk >> 7;            // 0 = pred, 1 = targ
    const int batch = (blk >> 4) & 7;
    const int chunk = blk & 15;
    const int n = chunk * 256 + tid;
    const float* base = (tensor ? targ : pred)
                        + (size_t)batch * NPTS * 10 + (size_t)n * 10;
    float2 f0 = *(const float2*)base;         // conf_raw, off_z
    float2 f1 = *(const float2*)(base + 2);   // off_x, off_y
    float gz = (float)(n >> 10);
    float gx = (float)((n >> 5) & 31);
    float gy = (float)(n & 31);

    bool active;
    unsigned long long key = 0;
    float4 rec;
    if (tensor == 0) {
        float conf = 1.0f / (1.0f + expf(-f0.x));   // jax.nn.sigmoid
        active = conf > 0.5f;
        unsigned int u = ~(__float_as_uint(conf) | 0x80000000u);  // conf desc
        key = ((unsigned long long)u << 32) | (unsigned int)n;    // idx asc
        rec = make_float4((f0.y + gz) * 0.25f,
                          (f1.x + gx) * 0.03125f,
                          (f1.y + gy) * 0.03125f,
                          (float)n);
    } else {
        active = f0.x > 0.5f;
        rec = make_float4((f0.y + gz) * 0.25f * 25.0f,
                          (f1.x + gx) * 0.03125f * 25.0f,
                          (f1.y + gy) * 0.03125f * 4.0f,
                          (float)n);
    }

    const int lane = tid & 63, wid = tid >> 6;
    unsigned long long ball = __ballot(active);
    int lofs = __popcll(ball & ((1ull << lane) - 1ull));
    if (lane == 0) wcnt[wid] = __popcll(ball);
    __syncthreads();
    int wb = 0;
    for (int w = 0; w < wid; ++w) wb += wcnt[w];
    if (tid == 0) {
        unsigned int t = (unsigned int)(wcnt[0] + wcnt[1] + wcnt[2] + wcnt[3]);
        (tensor ? tcc : pcc)[batch * 16 + chunk] = t;
    }
    if (active) {
        int e = batch * NPTS + chunk * 256 + wb + lofs;
        if (tensor == 0) { pkey[e] = key; ppos[e] = rec; }
        else tpos[e] = rec;
    }
}

// Main: one block per batch, compacted records only. Sort-free NMS (order via
// u64 keys); single-shot chunk loops with overflow fallback; benign-race LDS
// result stores (no same-address atomics, no mask reductions).
__global__ __launch_bounds__(NTH) void molan_kernel(const float* __restrict__ pred,
                                                    const float* __restrict__ targ,
                                                    const unsigned char* __restrict__ ws,
                                                    float* __restrict__ out) {
    __shared__ int   scr_i[32];
    __shared__ float scr_f[32];
    __shared__ int   cnt[4];
    __shared__ int   ccP[16], ccT[16];
    __shared__ unsigned long long f_key[NFILT];
    __shared__ float f_x[NFILT], f_y[NFILT], f_z[NFILT];
    __shared__ unsigned long long q_key[MAXQ];
    __shared__ float q_x[MAXQ], q_y[MAXQ], q_z[MAXQ];
    __shared__ int   q_res[MAXQ];
    __shared__ unsigned long long u_key[MAXU];
    __shared__ float u_x[MAXU], u_y[MAXU], u_z[MAXU];
    __shared__ float k_x[MAXK], k_y[MAXK], k_z[MAXK];
    __shared__ int   k_idx[MAXK];
    __shared__ unsigned int k_match[MAXK];

    const int b = blockIdx.x;
    const int tid = threadIdx.x;
    const float* pb = pred + (size_t)b * NPTS * 10;
    const float* tb = targ + (size_t)b * NPTS * 10;
    const unsigned long long* pkey = (const unsigned long long*)(ws + WS_PKEY) + b * NPTS;
    const float4* ppos = (const float4*)(ws + WS_PPOS) + b * NPTS;
    const float4* tpos = (const float4*)(ws + WS_TPOS) + b * NPTS;

    if (tid < 16) ccP[tid] = (int)((const unsigned int*)(ws + WS_PCC))[b * 16 + tid];
    else if (tid < 32) ccT[tid - 16] = (int)((const unsigned int*)(ws + WS_TCC))[b * 16 + tid - 16];
    __syncthreads();

    // ---- load compacted records into registers (chunk-local gating) ----
    unsigned long long key[SPT];
    bool  act[SPT];
    int   pidx[SPT];
    float cx[SPT], cy[SPT], cz[SPT];
    #pragma unroll
    for (int s = 0; s < SPT; ++s) {
        int slot = tid + NTH * s;
        bool a = (slot & 255) < ccP[slot >> 8];
        act[s] = a;
        key[s] = ~0ull;
        cx[s] = cy[s] = cz[s] = 0.f; pidx[s] = 0;
        if (a) {
            key[s] = pkey[slot];
            float4 p = ppos[slot];
            cx[s] = p.x; cy[s] = p.y; cz[s] = p.z; pidx[s] = (int)p.w;
        }
    }
    bool  t_act[SPT];
    int   t_n[SPT];
    float t_x[SPT], t_y[SPT], t_z[SPT];
    #pragma unroll
    for (int s = 0; s < SPT; ++s) {
        int slot = tid + NTH * s;
        bool a = (slot & 255) < ccT[slot >> 8];
        t_act[s] = a;
        t_x[s] = t_y[s] = t_z[s] = 0.f; t_n[s] = 0;
        if (a) {
            float4 p = tpos[slot];
            t_x[s] = p.x; t_y[s] = p.y; t_z[s] = p.z; t_n[s] = (int)p.w;
        }
    }

    // ---- NMS fixpoint (exact reference trajectory, order via keys) ----
    int loc = 0;
    #pragma unroll
    for (int s = 0; s < SPT; ++s) loc += act[s] ? 1 : 0;
    int cur = blockReduceSumI(loc, scr_i, tid);
    int prev = -1;
    while (cur != prev) {
        // filter = per-wave confidence champion (min key among actives)
        {
            unsigned long long bk = ~0ull;
            float bx = 0.f, by = 0.f, bz = 0.f;
            #pragma unroll
            for (int s = 0; s < SPT; ++s)
                if (act[s] && key[s] < bk) { bk = key[s]; bx = cx[s]; by = cy[s]; bz = cz[s]; }
            #pragma unroll
            for (int o = 32; o > 0; o >>= 1) {
                unsigned long long ok = __shfl_xor(bk, o, 64);
                float ox = __shfl_xor(bx, o, 64);
                float oy = __shfl_xor(by, o, 64);
                float oz = __shfl_xor(bz, o, 64);
                if (ok < bk) { bk = ok; bx = ox; by = oy; bz = oz; }
            }
            if ((tid & 63) == 0) {
                int w = tid >> 6;
                f_key[w] = bk; f_x[w] = bx; f_y[w] = by; f_z[w] = bz;
            }
        }
        __syncthreads();

        // pass 1: s[j] = exists active i (key_i<key_j) within cutoff
        bool sflag[SPT], pend[SPT];
        #pragma unroll
        for (int s = 0; s < SPT; ++s) {
            sflag[s] = false; pend[s] = false;
            if (!act[s]) continue;
            bool found = false;
            for (int f = 0; f < NFILT; ++f) {
                if (f_key[f] < key[s]) {
                    float dx = f_x[f] - cx[s], dy = f_y[f] - cy[s], dz = f_z[f] - cz[s];
                    if (dx * dx + dy * dy + dz * dz < 4.0f) { found = true; break; }
                }
            }
            if (found) sflag[s] = true;
            else pend[s] = true;
        }
        // single-shot cooperative resolve (overflow loops only if cnt > MAXQ)
        do {
            if (tid == 0) cnt[1] = 0;
            __syncthreads();   // fences prior q_* reads vs rewrites
            int qe[SPT];
            #pragma unroll
            for (int s = 0; s < SPT; ++s) {
                qe[s] = -1;
                if (pend[s]) {
                    int e = atomicAdd(&cnt[1], 1);
                    if (e < MAXQ) {
                        q_key[e] = key[s]; q_x[e] = cx[s]; q_y[e] = cy[s]; q_z[e] = cz[s];
                        q_res[e] = 0;
                        qe[s] = e; pend[s] = false;
                    }
                }
            }
            __syncthreads();
            const int Q = min(cnt[1], MAXQ);
            for (int e = 0; e < Q; ++e) {     // uniform loop
                unsigned long long qk = q_key[e];
                float qx = q_x[e], qy = q_y[e], qz = q_z[e];
                bool hit = false;
                #pragma unroll
                for (int s = 0; s < SPT; ++s) {
                    if (act[s] && key[s] < qk) {
                        float dx = cx[s] - qx, dy = cy[s] - qy, dz = cz[s] - qz;
                        if (dx * dx + dy * dy + dz * dz < 4.0f) hit = true;
                    }
                }
                if (hit) q_res[e] = 1;        // benign race: all writers store 1
            }
            __syncthreads();
            #pragma unroll
            for (int s = 0; s < SPT; ++s)
                if (qe[s] >= 0) sflag[s] = (q_res[qe[s]] != 0);
        } while (cnt[1] > MAXQ);

        // pass 2: supp[j] = exists u in U={active,!s} with key_u<key_j, d<cutoff
        bool upend[SPT], supp[SPT];
        #pragma unroll
        for (int s = 0; s < SPT; ++s) {
            upend[s] = act[s] && !sflag[s];
            supp[s] = false;
        }
        do {
            if (tid == 0) cnt[2] = 0;
            __syncthreads();   // fences prior u_* reads vs rewrites
            #pragma unroll
            for (int s = 0; s < SPT; ++s) {
                if (upend[s]) {
                    int e = atomicAdd(&cnt[2], 1);
                    if (e < MAXU) {
                        u_key[e] = key[s]; u_x[e] = cx[s]; u_y[e] = cy[s]; u_z[e] = cz[s];
                        upend[s] = false;
                    }
                }
            }
            __syncthreads();
            const int Ku = min(cnt[2], MAXU);
            #pragma unroll
            for (int s = 0; s < SPT; ++s) {
                if (!act[s] || supp[s]) continue;
                for (int e = 0; e < Ku; ++e) {
                    if (u_key[e] < key[s]) {
                        float dx = u_x[e] - cx[s], dy = u_y[e] - cy[s], dz = u_z[e] - cz[s];
                        if (dx * dx + dy * dy + dz * dz < 4.0f) { supp[s] = true; break; }
                    }
                }
            }
        } while (cnt[2] > MAXU);
        // commit
        loc = 0;
        #pragma unroll
        for (int s = 0; s < SPT; ++s) {
            if (act[s] && supp[s]) act[s] = false;
            loc += act[s] ? 1 : 0;
        }
        prev = cur;
        cur = blockReduceSumI(loc, scr_i, tid);
    }
    const int n_pd = cur;

    // ---- matching: kept preds vs all targets, lowest target idx wins ----
    bool kpend[SPT];
    #pragma unroll
    for (int s = 0; s < SPT; ++s) kpend[s] = act[s];
    int loc_tp = 0;
    float loc_ang = 0.0f;
    do {
        if (tid == 0) cnt[3] = 0;
        __syncthreads();   // fences prior k_* reads vs rewrites
        #pragma unroll
        for (int s = 0; s < SPT; ++s) {
            if (kpend[s]) {
                int e = atomicAdd(&cnt[3], 1);
                if (e < MAXK) {
                    k_x[e] = cx[s] * 25.0f; k_y[e] = cy[s] * 25.0f; k_z[e] = cz[s] * 4.0f;
                    k_idx[e] = pidx[s];
                    k_match[e] = 0xFFFFFFFFu;
                    kpend[s] = false;
                }
            }
        }
        __syncthreads();
        const int K = min(cnt[3], MAXK);
        #pragma unroll
        for (int s = 0; s < SPT; ++s) {
            if (!t_act[s]) continue;
            float tx = t_x[s], ty = t_y[s], tz = t_z[s];
            for (int e = 0; e < K; ++e) {
                float dx = tx - k_x[e], dy = ty - k_y[e], dz = tz - k_z[e];
                if (dx * dx + dy * dy + dz * dz < 4.0f)
                    atomicMin(&k_match[e], (unsigned int)t_n[s]);  // few hits
            }
        }
        __syncthreads();
        if (tid < K) {
            unsigned int m = k_match[tid];
            if (m != 0xFFFFFFFFu) {
                ++loc_tp;
                const float2* pr = (const float2*)(pb + (size_t)k_idx[tid] * 10 + 4);
                float2 p0 = pr[0], p1 = pr[1], p2v = pr[2];
                float ax0 = p0.x, ax1 = p0.y, ax2 = p1.x;
                float ay0 = p1.y, ay1 = p2v.x, ay2 = p2v.y;
                float az0 = ax1 * ay2 - ax2 * ay1;
                float az1 = ax2 * ay0 - ax0 * ay2;
                float az2 = ax0 * ay1 - ax1 * ay0;
                const float2* tr = (const float2*)(tb + (size_t)m * 10 + 4);
                float2 t0 = tr[0], t1 = tr[1], t2v = tr[2];
                float bx0 = t0.x, bx1 = t0.y, bx2 = t1.x;
                float by0 = t1.y, by1 = t2v.x, by2 = t2v.y;
                float bz0 = bx1 * by2 - bx2 * by1;
                float bz1 = bx2 * by0 - bx0 * by2;
                float bz2 = bx0 * by1 - bx1 * by0;
                loc_ang += rowAngleDeg(ax0, ax1, ax2, bx0, bx1, bx2);
                loc_ang += rowAngleDeg(ay0, ay1, ay2, by0, by1, by2);
                loc_ang += rowAngleDeg(az0, az1, az2, bz0, bz1, bz2);
            }
        }
    } while (cnt[3] > MAXK);

    int tp = blockReduceSumI(loc_tp, scr_i, tid);
    float angsum = blockReduceSumF(loc_ang, scr_f, tid);

    if (tid == 0) {
        int nt = 0;
        #pragma unroll
        for (int i = 0; i < 16; ++i) nt += ccT[i];
        out[b * 3 + 0] = (float)tp;
        out[b * 3 + 1] = (float)(n_pd - tp);
        out[b * 3 + 2] = (float)(nt - tp);
        out[NB * 3 + b] = (tp > 0) ? (angsum / (3.0f * (float)tp)) : 0.0f;
    }
}

extern "C" void kernel_launch(void* const* d_in, const int* in_sizes, int n_in,
                              void* d_out, int out_size, void* d_ws, size_t ws_size,
                              hipStream_t stream) {
    const float* pred = (const float*)d_in[0];
    const float* targ = (const float*)d_in[1];
    float* out = (float*)d_out;
    unsigned char* ws = (unsigned char*)d_ws;
    prep_kernel<<<dim3(256), dim3(256), 0, stream>>>(pred, targ, ws);
    molan_kernel<<<dim3(NB), dim3(NTH), 0, stream>>>(pred, targ, ws, out);
}